// Round 1
// baseline (412.122 us; speedup 1.0000x reference)
//
#include <hip/hip_runtime.h>
#include <hip/hip_bf16.h>
#include <math.h>

#define M_HALF 2097152          // 2^21, half-length complex IFFT size
#define NQ     262144           // M_HALF / 8, threads per FFT pass

typedef __bf16 bf16_t;
typedef __attribute__((ext_vector_type(8))) __bf16 bf8;
typedef __attribute__((ext_vector_type(4))) __bf16 bf4;
typedef __attribute__((ext_vector_type(4))) float f32x4;

#define GLOBAL_AS __attribute__((address_space(1)))
#define LDS_AS    __attribute__((address_space(3)))

__device__ __forceinline__ float2 cadd(float2 a, float2 b){ return make_float2(a.x+b.x, a.y+b.y); }
__device__ __forceinline__ float2 csub(float2 a, float2 b){ return make_float2(a.x-b.x, a.y-b.y); }
__device__ __forceinline__ float2 cmul(float2 a, float2 b){ return make_float2(a.x*b.x-a.y*b.y, a.x*b.y+a.y*b.x); }
__device__ __forceinline__ float2 cmuli(float2 a){ return make_float2(-a.y, a.x); } // *(+i)

// ---------------- zero / scatter / preprocess ----------------

__global__ __launch_bounds__(256) void zero2_kernel(float2* p, int n) {
    int i = blockIdx.x*256 + threadIdx.x;
    if (i < n) p[i] = make_float2(0.f, 0.f);
}

__global__ __launch_bounds__(256) void scatter_kernel(const float* __restrict__ cr,
                                                      const float* __restrict__ ci,
                                                      const int* __restrict__ idx,
                                                      float2* __restrict__ spec, int keep) {
    int i = blockIdx.x*256 + threadIdx.x;
    if (i < keep) {
        int k = idx[i];
        spec[k] = make_float2(cr[i], ci[i]);
    }
}

// Z[k] = E[k] + i*O[k],  E=(X[k]+conj(X[M-k]))/2, O=(X[k]-conj(X[M-k]))/2 * e^{+i pi k/M}
// scaled by scale/M (irfft 1/N normalization folded with half-size split).
__global__ __launch_bounds__(256) void prep_kernel(const float2* __restrict__ spec,
                                                   float2* __restrict__ Z,
                                                   const float* __restrict__ scale) {
    int k = blockIdx.x*256 + threadIdx.x;
    float2 a = spec[k];
    float2 b = spec[M_HALF - k];
    if (k == 0) { a.y = 0.0f; b.y = 0.0f; }   // c2r ignores imag of DC & Nyquist
    float Er = 0.5f*(a.x + b.x), Ei = 0.5f*(a.y - b.y);
    float Tr = 0.5f*(a.x - b.x), Ti = 0.5f*(a.y + b.y);
    float ang = (float)(3.14159265358979323846 * (double)k / (double)M_HALF);
    float sn, cs; sincosf(ang, &sn, &cs);
    float Or = Tr*cs - Ti*sn;
    float Oi = Tr*sn + Ti*cs;
    float s = scale[0] * (1.0f/(float)M_HALF);
    Z[k] = make_float2((Er - Oi)*s, (Ei + Or)*s);
}

// ---------------- radix-8 Stockham inverse FFT pass ----------------
// Inverse (e^{+i...}), no per-pass scaling. Output natural order after all passes.
template<int NS>
__global__ __launch_bounds__(256) void ifft_pass8(const float2* __restrict__ src,
                                                  float2* __restrict__ dst) {
    int j = blockIdx.x*256 + threadIdx.x;   // j < NQ
    float2 v[8];
#pragma unroll
    for (int t = 0; t < 8; ++t) v[t] = src[j + t*NQ];
    int jm = j & (NS - 1);
    if constexpr (NS > 1) {
        double base = (double)jm / (double)(NS * 8);
#pragma unroll
        for (int t = 1; t < 8; ++t) {
            float ang = (float)(6.283185307179586 * base * (double)t);
            float sn, cs; sincosf(ang, &sn, &cs);
            v[t] = cmul(v[t], make_float2(cs, sn));
        }
    }
    const float cc = 0.70710678118654752f;
    // DIF radix-8, inverse sign, natural-order outputs
    float2 a0 = cadd(v[0], v[4]), a1 = cadd(v[1], v[5]), a2 = cadd(v[2], v[6]), a3 = cadd(v[3], v[7]);
    float2 b0 = csub(v[0], v[4]), b1 = csub(v[1], v[5]), b2 = csub(v[2], v[6]), b3 = csub(v[3], v[7]);
    b1 = cmul(b1, make_float2(cc, cc));    // e^{+i pi/4}
    b2 = cmuli(b2);                        // e^{+i pi/2}
    b3 = cmul(b3, make_float2(-cc, cc));   // e^{+i 3pi/4}
    float2 c0 = cadd(a0, a2), c1 = cadd(a1, a3), d0 = csub(a0, a2), d1 = cmuli(csub(a1, a3));
    float2 e0 = cadd(b0, b2), e1 = cadd(b1, b3), f0 = csub(b0, b2), f1 = cmuli(csub(b1, b3));
    float2 X0 = cadd(c0, c1), X4 = csub(c0, c1), X2 = cadd(d0, d1), X6 = csub(d0, d1);
    float2 X1 = cadd(e0, e1), X5 = csub(e0, e1), X3 = cadd(f0, f1), X7 = csub(f0, f1);
    int idxD = ((j - jm) << 3) + jm;
    dst[idxD + 0*NS] = X0;
    dst[idxD + 1*NS] = X1;
    dst[idxD + 2*NS] = X2;
    dst[idxD + 3*NS] = X3;
    dst[idxD + 4*NS] = X4;
    dst[idxD + 5*NS] = X5;
    dst[idxD + 6*NS] = X6;
    dst[idxD + 7*NS] = X7;
}

// ---------------- transpose fp32 -> bf16 (w[R][C] -> wT[C][R]) ----------------

__global__ __launch_bounds__(256) void transpose_kernel(const float* __restrict__ w,
                                                        bf16_t* __restrict__ wT,
                                                        int R, int C) {
    __shared__ float tile[32][33];
    int tx = threadIdx.x & 31, ty = threadIdx.x >> 5;   // ty 0..7
    long c0 = (long)blockIdx.x * 32, r0 = (long)blockIdx.y * 32;
#pragma unroll
    for (int i = 0; i < 4; ++i)
        tile[ty + i*8][tx] = w[(r0 + ty + i*8) * C + c0 + tx];
    __syncthreads();
#pragma unroll
    for (int i = 0; i < 4; ++i) {
        int c = ty + i*8;
        wT[(c0 + c) * R + r0 + tx] = (bf16_t)tile[tx][c];
    }
}

// ---------------- fp32 -> bf16 convert (x) ----------------

__global__ __launch_bounds__(256) void cvt_bf16_kernel(const float* __restrict__ in,
                                                       bf16_t* __restrict__ out, int n4) {
    int i = blockIdx.x*256 + threadIdx.x;
    if (i < n4) {
        float4 v = ((const float4*)in)[i];
        bf4 o;
        o[0] = (bf16_t)v.x; o[1] = (bf16_t)v.y; o[2] = (bf16_t)v.z; o[3] = (bf16_t)v.w;
        ((bf4*)out)[i] = o;
    }
}

// ---------------- MFMA GEMM: C = A[M][K] * Bt[N][K]^T ----------------

__device__ __forceinline__ void stage_tile(const bf16_t* g, int ld, int row0, int col0,
                                           bf16_t* lds, int tid) {
    // tile 128 rows x 64 cols bf16, LDS row-major [128][64]
    int w = tid >> 6, l = tid & 63;
#pragma unroll
    for (int i = 0; i < 4; ++i) {
        int chunk = (i << 2) + w;          // 0..15, each 512 elems (1 KiB)
        int e = (chunk << 9) + (l << 3);   // element offset this lane stages
        int r = e >> 6, c = e & 63;
        const bf16_t* ga = g + (long)(row0 + r) * ld + col0 + c;
        bf16_t* la = lds + (chunk << 9);   // wave-uniform LDS base
        __builtin_amdgcn_global_load_lds((const GLOBAL_AS unsigned int*)ga,
                                         (LDS_AS unsigned int*)la, 16, 0, 0);
    }
}

template<int EPI>  // 0: bias+gelu -> bf16 ; 1: bias -> fp32
__global__ __launch_bounds__(256) void gemm_bt(const bf16_t* __restrict__ A,
                                               const bf16_t* __restrict__ Bt,
                                               const float* __restrict__ bias,
                                               void* __restrict__ Cout,
                                               int M, int N, int K) {
    __shared__ __align__(16) bf16_t lA[128*64];
    __shared__ __align__(16) bf16_t lB[128*64];
    const int tid = threadIdx.x;
    const int l = tid & 63, w = tid >> 6;
    const int wr = w >> 1, wc = w & 1;
    const int row0 = blockIdx.y * 128, col0 = blockIdx.x * 128;
    f32x4 acc[4][4] = {};
    for (int k0 = 0; k0 < K; k0 += 64) {
        stage_tile(A,  K, row0, k0, lA, tid);
        stage_tile(Bt, K, col0, k0, lB, tid);
        __syncthreads();
#pragma unroll
        for (int kk = 0; kk < 64; kk += 32) {
            bf8 af[4], bfr[4];
            const int lr = l & 15, lk = kk + ((l >> 4) << 3);
#pragma unroll
            for (int mi = 0; mi < 4; ++mi)
                af[mi] = *(const bf8*)&lA[(wr*64 + mi*16 + lr)*64 + lk];
#pragma unroll
            for (int ni = 0; ni < 4; ++ni)
                bfr[ni] = *(const bf8*)&lB[(wc*64 + ni*16 + lr)*64 + lk];
#pragma unroll
            for (int mi = 0; mi < 4; ++mi)
#pragma unroll
                for (int ni = 0; ni < 4; ++ni)
                    acc[mi][ni] = __builtin_amdgcn_mfma_f32_16x16x32_bf16(
                        af[mi], bfr[ni], acc[mi][ni], 0, 0, 0);
        }
        __syncthreads();
    }
    // epilogue: C/D layout col=lane&15, row=(lane>>4)*4+reg
    const int fr = l & 15, fq = l >> 4;
#pragma unroll
    for (int mi = 0; mi < 4; ++mi) {
#pragma unroll
        for (int ni = 0; ni < 4; ++ni) {
#pragma unroll
            for (int q = 0; q < 4; ++q) {
                int r = row0 + wr*64 + mi*16 + fq*4 + q;
                int c = col0 + wc*64 + ni*16 + fr;
                float v = acc[mi][ni][q] + bias[c];
                if constexpr (EPI == 0) {
                    v = 0.5f * v * (1.0f + erff(v * 0.70710678118654752f));
                    ((bf16_t*)Cout)[(long)r * N + c] = (bf16_t)v;
                } else {
                    ((float*)Cout)[(long)r * N + c] = v;
                }
            }
        }
    }
}

// ---------------- launch ----------------

extern "C" void kernel_launch(void* const* d_in, const int* in_sizes, int n_in,
                              void* d_out, int out_size, void* d_ws, size_t ws_size,
                              hipStream_t stream) {
    const float* x        = (const float*)d_in[0];
    const float* fc_cr    = (const float*)d_in[1];
    const float* fc_ci    = (const float*)d_in[2];
    const int*   fc_idx   = (const int*)  d_in[3];
    const float* fc_scale = (const float*)d_in[4];
    const float* fc_bias  = (const float*)d_in[5];
    const float* pj_cr    = (const float*)d_in[6];
    const float* pj_ci    = (const float*)d_in[7];
    const int*   pj_idx   = (const int*)  d_in[8];
    const float* pj_scale = (const float*)d_in[9];
    const float* pj_bias  = (const float*)d_in[10];
    const int keep = in_sizes[1];

    char* ws = (char*)d_ws;
    bf16_t* w_fcT = (bf16_t*)(ws + 0);          //  8,388,608 B  [4096][1024]
    bf16_t* w_pjT = (bf16_t*)(ws + 8388608);    //  8,388,608 B  [1024][4096]
    bf16_t* x_bf  = (bf16_t*)(ws + 16777216);   // 16,777,216 B  [8192][1024]
    bf16_t* h_bf  = (bf16_t*)(ws + 33554432);   // 67,108,864 B  [8192][4096]
    // FFT scratch aliased over h_bf region (all FFT work finishes before GEMM1)
    float2* spec  = (float2*)(ws + 33554432);   // (2^21+1)*8 B
    float2* fftA  = (float2*)(ws + 50331904);   // 16,777,216 B
    float2* fftB  = (float2*)(ws + 67109120);   // 16,777,216 B

    auto run_decompress = [&](const float* cr, const float* ci, const int* idx,
                              const float* scale, bf16_t* wT, int R, int C) {
        zero2_kernel<<<(M_HALF + 1 + 255)/256, 256, 0, stream>>>(spec, M_HALF + 1);
        scatter_kernel<<<(keep + 255)/256, 256, 0, stream>>>(cr, ci, idx, spec, keep);
        prep_kernel<<<M_HALF/256, 256, 0, stream>>>(spec, fftA, scale);
        ifft_pass8<1>     <<<NQ/256, 256, 0, stream>>>(fftA, fftB);
        ifft_pass8<8>     <<<NQ/256, 256, 0, stream>>>(fftB, fftA);
        ifft_pass8<64>    <<<NQ/256, 256, 0, stream>>>(fftA, fftB);
        ifft_pass8<512>   <<<NQ/256, 256, 0, stream>>>(fftB, fftA);
        ifft_pass8<4096>  <<<NQ/256, 256, 0, stream>>>(fftA, fftB);
        ifft_pass8<32768> <<<NQ/256, 256, 0, stream>>>(fftB, fftA);
        ifft_pass8<262144><<<NQ/256, 256, 0, stream>>>(fftA, fftB);
        dim3 tg(C/32, R/32);
        transpose_kernel<<<tg, 256, 0, stream>>>((const float*)fftB, wT, R, C);
    };

    run_decompress(fc_cr, fc_ci, fc_idx, fc_scale, w_fcT, 1024, 4096);
    run_decompress(pj_cr, pj_ci, pj_idx, pj_scale, w_pjT, 4096, 1024);

    cvt_bf16_kernel<<<8388608/4/256, 256, 0, stream>>>(x, x_bf, 8388608/4);

    gemm_bt<0><<<dim3(4096/128, 8192/128), 256, 0, stream>>>(
        x_bf, w_fcT, fc_bias, h_bf, 8192, 4096, 1024);
    gemm_bt<1><<<dim3(1024/128, 8192/128), 256, 0, stream>>>(
        h_bf, w_pjT, pj_bias, d_out, 8192, 1024, 4096);

    (void)n_in; (void)out_size; (void)ws_size;
}